// Round 3
// baseline (256.121 us; speedup 1.0000x reference)
//
#include <hip/hip_runtime.h>
#include <hip/hip_cooperative_groups.h>
#include <math.h>

namespace cg = cooperative_groups;

#define VOCAB   50265
#define D       768
#define N_NEW   200
#define N_NODES 199
#define N_EDGES 1024
#define LEAKY   0.2f

// ---- GEMM split-K config ----
#define ROW_T 4      // rows per block
#define KC    4      // K chunks
#define KLEN  192    // 768 / KC
#define NROWT 50     // ceil(199/4)
#define GAT_BLOCKS (NROWT * 3 * KC)   // 600

// One cooperative kernel for the whole GAT:
// Phase 1: split-K GEMM partials (600 blocks)
// Phase 2: reduce partials -> h, sv, dv (199 blocks)
// Phase 3: edge softmax + CSR build (block 0)
// Phase 4: aggregate + elu + residual -> gfeats (199 blocks)
__global__ __launch_bounds__(256) void gat_coop_kernel(
    const float* __restrict__ new_emb, const float* __restrict__ W,
    const float* __restrict__ a_src, const float* __restrict__ a_dst,
    const int* __restrict__ edge_index,
    float* __restrict__ partial, float* __restrict__ h,
    float* __restrict__ sv, float* __restrict__ dv,
    float* __restrict__ alpha, float* __restrict__ gfeats,
    int* __restrict__ csr_off, int* __restrict__ csr_eid)
{
    cg::grid_group grid = cg::this_grid();
    const int tid = threadIdx.x;
    const int bid = blockIdx.x;

    // ---------------- Phase 1: gemm partial ----------------
    {
        __shared__ float fts[ROW_T][KLEN];
        const int rowt = bid % NROWT;
        const int colt = (bid / NROWT) % 3;
        const int kc   = bid / (NROWT * 3);
        const int row0 = rowt * ROW_T;
        const int col  = colt * 256 + tid;
        const int k0   = kc * KLEN;

        for (int i = tid; i < ROW_T * KLEN; i += 256) {
            int r  = i / KLEN;
            int kk = i - r * KLEN;
            int row = row0 + r;
            fts[r][kk] = (row < N_NODES) ? new_emb[(size_t)(1 + row) * D + k0 + kk] : 0.f;
        }
        __syncthreads();

        float acc0 = 0.f, acc1 = 0.f, acc2 = 0.f, acc3 = 0.f;
        #pragma unroll 4
        for (int kk = 0; kk < KLEN; ++kk) {
            float w = W[(size_t)(k0 + kk) * D + col];
            acc0 = fmaf(fts[0][kk], w, acc0);
            acc1 = fmaf(fts[1][kk], w, acc1);
            acc2 = fmaf(fts[2][kk], w, acc2);
            acc3 = fmaf(fts[3][kk], w, acc3);
        }

        const size_t base = ((size_t)kc * N_NODES) * D + col;
        if (row0 + 0 < N_NODES) partial[base + (size_t)(row0 + 0) * D] = acc0;
        if (row0 + 1 < N_NODES) partial[base + (size_t)(row0 + 1) * D] = acc1;
        if (row0 + 2 < N_NODES) partial[base + (size_t)(row0 + 2) * D] = acc2;
        if (row0 + 3 < N_NODES) partial[base + (size_t)(row0 + 3) * D] = acc3;
    }
    grid.sync();

    // ---------------- Phase 2: reduce -> h, sv, dv ----------------
    if (bid < N_NODES) {
        __shared__ float redS[4], redD[4];
        const int row = bid;
        const size_t kcstride = (size_t)N_NODES * D;

        float hv[3];
        #pragma unroll
        for (int j = 0; j < 3; ++j) {
            const size_t idx = (size_t)row * D + tid + j * 256;
            float s = partial[idx];
            s += partial[idx + kcstride];
            s += partial[idx + 2 * kcstride];
            s += partial[idx + 3 * kcstride];
            hv[j] = s;
            h[idx] = s;
        }

        float ps = hv[0] * a_src[tid] + hv[1] * a_src[tid + 256] + hv[2] * a_src[tid + 512];
        float pd = hv[0] * a_dst[tid] + hv[1] * a_dst[tid + 256] + hv[2] * a_dst[tid + 512];
        #pragma unroll
        for (int off = 32; off; off >>= 1) {
            ps += __shfl_down(ps, off, 64);
            pd += __shfl_down(pd, off, 64);
        }
        if ((tid & 63) == 0) { redS[tid >> 6] = ps; redD[tid >> 6] = pd; }
        __syncthreads();
        if (tid == 0) {
            sv[row] = redS[0] + redS[1] + redS[2] + redS[3];
            dv[row] = redD[0] + redD[1] + redD[2] + redD[3];
        }
    }
    grid.sync();

    // ---------------- Phase 3: softmax + CSR (block 0) ----------------
    if (bid == 0) {
        __shared__ float e[N_EDGES];
        __shared__ short sdst[N_EDGES];
        __shared__ float m[N_NODES];
        __shared__ float denom[N_NODES];
        __shared__ int   off[N_NODES + 1];
        __shared__ int   cursor[N_NODES];
        __shared__ int   eid[N_EDGES];

        for (int n = tid; n < N_NODES; n += 256) cursor[n] = 0;
        __syncthreads();

        for (int k = tid; k < N_EDGES; k += 256) {
            int s = edge_index[k];
            int d = edge_index[N_EDGES + k];
            sdst[k] = (short)d;
            float ev = sv[s] + dv[d];
            e[k] = ev > 0.f ? ev : LEAKY * ev;
            atomicAdd(&cursor[d], 1);
        }
        __syncthreads();

        if (tid == 0) {
            int run = 0;
            for (int n = 0; n < N_NODES; ++n) { off[n] = run; run += cursor[n]; }
            off[N_NODES] = run;
        }
        __syncthreads();
        for (int n = tid; n < N_NODES; n += 256) cursor[n] = off[n];
        __syncthreads();

        for (int k = tid; k < N_EDGES; k += 256) {
            int pos = atomicAdd(&cursor[(int)sdst[k]], 1);
            eid[pos] = k;
        }
        __syncthreads();

        for (int n = tid; n < N_NODES; n += 256) {
            float mx = -INFINITY;
            for (int p = off[n]; p < off[n + 1]; ++p) mx = fmaxf(mx, e[eid[p]]);
            float dn = 0.f;
            for (int p = off[n]; p < off[n + 1]; ++p) dn += expf(e[eid[p]] - mx);
            m[n] = mx;
            denom[n] = dn;
        }
        __syncthreads();

        for (int k = tid; k < N_EDGES; k += 256) {
            int d = (int)sdst[k];
            alpha[k] = expf(e[k] - m[d]) / fmaxf(denom[d], 1e-9f);
        }
        for (int n = tid; n < N_NODES + 1; n += 256) csr_off[n] = off[n];
        for (int k = tid; k < N_EDGES; k += 256)     csr_eid[k] = eid[k];
    }
    grid.sync();

    // ---------------- Phase 4: aggregate + elu + residual ----------------
    if (bid < N_NODES) {
        const int n = bid;
        const int p0 = csr_off[n], p1 = csr_off[n + 1];

        float a0 = 0.f, a1 = 0.f, a2 = 0.f;
        for (int p = p0; p < p1; ++p) {
            const int k = csr_eid[p];
            const float a = alpha[k];
            const float* hs = h + (size_t)edge_index[k] * D;
            a0 = fmaf(a, hs[tid], a0);
            a1 = fmaf(a, hs[tid + 256], a1);
            a2 = fmaf(a, hs[tid + 512], a2);
        }
        const float* f = new_emb + (size_t)(1 + n) * D;
        float e0 = a0 > 0.f ? a0 : expf(a0) - 1.f;
        float e1 = a1 > 0.f ? a1 : expf(a1) - 1.f;
        float e2 = a2 > 0.f ? a2 : expf(a2) - 1.f;
        gfeats[(size_t)n * D + tid]       = e0 + f[tid];
        gfeats[(size_t)n * D + tid + 256] = e1 + f[tid + 256];
        gfeats[(size_t)n * D + tid + 512] = e2 + f[tid + 512];
    }
}

// ---------------- Gather: one wave per token, 3 float4/lane ----------------
__global__ __launch_bounds__(256) void gather_kernel(
    const int* __restrict__ x, const float* __restrict__ orig_emb,
    const float* __restrict__ gfeats, const float* __restrict__ new_emb,
    float* __restrict__ out, int ntok)
{
    const int token = blockIdx.x * 4 + (threadIdx.x >> 6);
    if (token >= ntok) return;
    const int lane = threadIdx.x & 63;
    const int idx = x[token];

    const float4* src;
    if (idx < VOCAB)
        src = (const float4*)(orig_emb + (size_t)idx * D);
    else if (idx < VOCAB + N_NODES)
        src = (const float4*)(gfeats + (size_t)(idx - VOCAB) * D);
    else
        src = (const float4*)(new_emb + (size_t)N_NEW * D);

    float4* dst = (float4*)(out + (size_t)token * D);
    dst[lane]       = src[lane];
    dst[lane + 64]  = src[lane + 64];
    dst[lane + 128] = src[lane + 128];
}

extern "C" void kernel_launch(void* const* d_in, const int* in_sizes, int n_in,
                              void* d_out, int out_size, void* d_ws, size_t ws_size,
                              hipStream_t stream) {
    const int*   x        = (const int*)  d_in[0];
    const float* orig_emb = (const float*)d_in[1];
    const float* new_emb  = (const float*)d_in[2];
    const float* W        = (const float*)d_in[3];
    const float* a_src    = (const float*)d_in[4];
    const float* a_dst    = (const float*)d_in[5];
    const int*   edge_idx = (const int*)  d_in[6];
    float* out = (float*)d_out;

    // workspace layout (floats)
    float* ws      = (float*)d_ws;
    float* h       = ws;                               // 199*768
    float* sv      = h + (size_t)N_NODES * D;          // 199
    float* dv      = sv + N_NODES;                     // 199
    float* alpha   = dv + N_NODES;                     // 1024
    float* gfeats  = alpha + N_EDGES;                  // 199*768
    float* partial = gfeats + (size_t)N_NODES * D;     // 4*199*768
    int*   csr_off = (int*)(partial + (size_t)KC * N_NODES * D);  // 200
    int*   csr_eid = csr_off + (N_NODES + 1);                     // 1024

    const int ntok = in_sizes[0];                      // 8*4096 = 32768

    void* args[] = {
        (void*)&new_emb, (void*)&W, (void*)&a_src, (void*)&a_dst,
        (void*)&edge_idx, (void*)&partial, (void*)&h, (void*)&sv,
        (void*)&dv, (void*)&alpha, (void*)&gfeats, (void*)&csr_off,
        (void*)&csr_eid
    };
    hipLaunchCooperativeKernel((void*)gat_coop_kernel, dim3(GAT_BLOCKS),
                               dim3(256), args, 0, stream);

    gather_kernel<<<(ntok + 3) / 4, 256, 0, stream>>>(
        x, orig_emb, gfeats, new_emb, out, ntok);
}